// Round 1
// baseline (79.249 us; speedup 1.0000x reference)
//
#include <hip/hip_runtime.h>
#include <math.h>

// Pack scan points as float4 {2x, 2y, 2z, -(x^2+y^2+z^2)} so the inner loop is
// q = 2*t.s - |s|^2 via 3 fma, and d2min = |t|^2 - max(q).
__global__ void pack_scan(const float* __restrict__ scan,
                          float4* __restrict__ packed, int N) {
    int i = blockIdx.x * blockDim.x + threadIdx.x;
    if (i < N) {
        float x = scan[3 * i + 0];
        float y = scan[3 * i + 1];
        float z = scan[3 * i + 2];
        packed[i] = make_float4(2.f * x, 2.f * y, 2.f * z,
                                -(x * x + y * y + z * z));
    }
}

// Each thread owns one template point; loops over a wave-uniform scan chunk.
// Scan loads are uniform-address -> scalar s_load_dwordx4 (free on VALU pipe).
// 4 independent accumulators break the fma->max dependence chain.
__global__ void __launch_bounds__(256) chamfer_main(
    const float* __restrict__ tmpl, const float4* __restrict__ packed,
    float* __restrict__ part, int M, int N, int chunk) {
    int m = blockIdx.x * blockDim.x + threadIdx.x;
    int c = blockIdx.y;
    int j0 = c * chunk;
    int j1 = j0 + chunk;
    if (j1 > N) j1 = N;

    float tx = 0.f, ty = 0.f, tz = 0.f;
    if (m < M) {
        tx = tmpl[3 * m + 0];
        ty = tmpl[3 * m + 1];
        tz = tmpl[3 * m + 2];
    }

    float q0 = -INFINITY, q1 = -INFINITY, q2 = -INFINITY, q3 = -INFINITY;
    int j = j0;
    for (; j + 3 < j1; j += 4) {
        float4 p0 = packed[j + 0];
        float4 p1 = packed[j + 1];
        float4 p2 = packed[j + 2];
        float4 p3 = packed[j + 3];
        q0 = fmaxf(q0, fmaf(tx, p0.x, fmaf(ty, p0.y, fmaf(tz, p0.z, p0.w))));
        q1 = fmaxf(q1, fmaf(tx, p1.x, fmaf(ty, p1.y, fmaf(tz, p1.z, p1.w))));
        q2 = fmaxf(q2, fmaf(tx, p2.x, fmaf(ty, p2.y, fmaf(tz, p2.z, p2.w))));
        q3 = fmaxf(q3, fmaf(tx, p3.x, fmaf(ty, p3.y, fmaf(tz, p3.z, p3.w))));
    }
    for (; j < j1; ++j) {
        float4 p = packed[j];
        q0 = fmaxf(q0, fmaf(tx, p.x, fmaf(ty, p.y, fmaf(tz, p.z, p.w))));
    }
    float qmax = fmaxf(fmaxf(q0, q1), fmaxf(q2, q3));
    if (m < M) part[(size_t)c * M + m] = qmax;
}

// Per-template reduction over chunks + per-block partial sum (deterministic).
__global__ void __launch_bounds__(256) chamfer_reduce(
    const float* __restrict__ tmpl, const float* __restrict__ part,
    float* __restrict__ blockSums, int M, int NC) {
    int m = blockIdx.x * blockDim.x + threadIdx.x;
    float d2 = 0.f;
    if (m < M) {
        float qmax = -INFINITY;
        for (int c = 0; c < NC; ++c)
            qmax = fmaxf(qmax, part[(size_t)c * M + m]);
        float x = tmpl[3 * m + 0];
        float y = tmpl[3 * m + 1];
        float z = tmpl[3 * m + 2];
        float tsq = x * x + y * y + z * z;
        d2 = tsq - qmax;
        if (d2 < 0.f) d2 = 0.f;
    }
    // wave (64-lane) shuffle reduce, then cross-wave via LDS
    for (int off = 32; off >= 1; off >>= 1) d2 += __shfl_down(d2, off, 64);
    __shared__ float wsum[4];
    int lane = threadIdx.x & 63;
    int wid = threadIdx.x >> 6;
    if (lane == 0) wsum[wid] = d2;
    __syncthreads();
    if (threadIdx.x == 0)
        blockSums[blockIdx.x] = wsum[0] + wsum[1] + wsum[2] + wsum[3];
}

__global__ void final_sum(const float* __restrict__ blockSums,
                          float* __restrict__ out, int nb) {
    float s = 0.f;
    for (int i = threadIdx.x; i < nb; i += 64) s += blockSums[i];
    for (int off = 32; off >= 1; off >>= 1) s += __shfl_down(s, off, 64);
    if (threadIdx.x == 0) out[0] = s;
}

extern "C" void kernel_launch(void* const* d_in, const int* in_sizes, int n_in,
                              void* d_out, int out_size, void* d_ws,
                              size_t ws_size, hipStream_t stream) {
    const float* scan = (const float*)d_in[0];   // [N,3]
    const float* tmpl = (const float*)d_in[1];   // [M,3]
    int N = in_sizes[0] / 3;
    int M = in_sizes[1] / 3;
    float* out = (float*)d_out;

    int MB = (M + 255) / 256;

    // pick NC (scan chunks) that fits the workspace; prefer 32 (=> 5 blocks/CU)
    int NC = 32;
    while (NC > 1) {
        size_t need = (size_t)N * 16 + (size_t)NC * M * 4 + (size_t)MB * 4;
        if (need <= ws_size) break;
        NC >>= 1;
    }

    char* ws = (char*)d_ws;
    float4* packed = (float4*)ws;
    size_t off = (size_t)N * 16;
    float* part = (float*)(ws + off);
    off += (size_t)NC * M * 4;
    float* blockSums = (float*)(ws + off);

    pack_scan<<<(N + 255) / 256, 256, 0, stream>>>(scan, packed, N);

    int chunk = (N + NC - 1) / NC;
    dim3 grid(MB, NC);
    chamfer_main<<<grid, 256, 0, stream>>>(tmpl, packed, part, M, N, chunk);

    chamfer_reduce<<<MB, 256, 0, stream>>>(tmpl, part, blockSums, M, NC);
    final_sum<<<1, 64, 0, stream>>>(blockSums, out, MB);
}

// Round 2
// 56.176 us; speedup vs baseline: 1.4107x; 1.4107x over previous
//
#include <hip/hip_runtime.h>
#include <math.h>

// Directional Chamfer. d2[m,n] = |t|^2 - (2 t.s - |s|^2).
// Main kernel: each thread owns T=4 template points; scan chunk staged in LDS
// as float4 {2x,2y,2z,-|s|^2} (pack fused into staging). Inner loop per scan
// point: 1 broadcast ds_read_b128 + 16 VALU (4 tpl x (3 fma + 1 max)).

#define TPT 4           // template points per thread
#define BLK 256         // threads per block
#define MPB (TPT * BLK) // template points per block = 1024

__global__ void __launch_bounds__(BLK) chamfer_main(
    const float* __restrict__ scan, const float* __restrict__ tmpl,
    float* __restrict__ part, int M, int N, int chunk) {
    extern __shared__ float4 lds[];

    int c = blockIdx.y;
    int j0 = c * chunk;
    int j1 = j0 + chunk;
    if (j1 > N) j1 = N;
    int cnt = j1 - j0;
    if (cnt < 0) cnt = 0;

    // Stage + pack this block's scan chunk into LDS.
    for (int i = threadIdx.x; i < cnt; i += BLK) {
        float x = scan[3 * (j0 + i) + 0];
        float y = scan[3 * (j0 + i) + 1];
        float z = scan[3 * (j0 + i) + 2];
        lds[i] = make_float4(2.f * x, 2.f * y, 2.f * z,
                             -(x * x + y * y + z * z));
    }
    __syncthreads();

    // Load TPT template points (strided by BLK -> coalesced 12B/lane).
    int base = blockIdx.x * MPB + threadIdx.x;
    float tx[TPT], ty[TPT], tz[TPT];
#pragma unroll
    for (int k = 0; k < TPT; ++k) {
        int m = base + k * BLK;
        if (m < M) {
            tx[k] = tmpl[3 * m + 0];
            ty[k] = tmpl[3 * m + 1];
            tz[k] = tmpl[3 * m + 2];
        } else {
            tx[k] = ty[k] = tz[k] = 0.f;
        }
    }

    float q[TPT];
#pragma unroll
    for (int k = 0; k < TPT; ++k) q[k] = -INFINITY;

#pragma unroll 4
    for (int j = 0; j < cnt; ++j) {
        float4 p = lds[j];  // broadcast: all lanes same address, conflict-free
#pragma unroll
        for (int k = 0; k < TPT; ++k)
            q[k] = fmaxf(q[k],
                         fmaf(tx[k], p.x, fmaf(ty[k], p.y, fmaf(tz[k], p.z, p.w))));
    }

#pragma unroll
    for (int k = 0; k < TPT; ++k) {
        int m = base + k * BLK;
        if (m < M) part[(size_t)c * M + m] = q[k];
    }
}

// Per-template min over chunks + deterministic per-block partial sums.
__global__ void __launch_bounds__(256) chamfer_reduce(
    const float* __restrict__ tmpl, const float* __restrict__ part,
    float* __restrict__ blockSums, int M, int NC) {
    int m = blockIdx.x * blockDim.x + threadIdx.x;
    float d2 = 0.f;
    if (m < M) {
        float qmax = -INFINITY;
        for (int c = 0; c < NC; ++c)
            qmax = fmaxf(qmax, part[(size_t)c * M + m]);
        float x = tmpl[3 * m + 0];
        float y = tmpl[3 * m + 1];
        float z = tmpl[3 * m + 2];
        float tsq = x * x + y * y + z * z;
        d2 = tsq - qmax;
        if (d2 < 0.f) d2 = 0.f;
    }
    for (int off = 32; off >= 1; off >>= 1) d2 += __shfl_down(d2, off, 64);
    __shared__ float wsum[4];
    int lane = threadIdx.x & 63;
    int wid = threadIdx.x >> 6;
    if (lane == 0) wsum[wid] = d2;
    __syncthreads();
    if (threadIdx.x == 0)
        blockSums[blockIdx.x] = wsum[0] + wsum[1] + wsum[2] + wsum[3];
}

__global__ void final_sum(const float* __restrict__ blockSums,
                          float* __restrict__ out, int nb) {
    float s = 0.f;
    for (int i = threadIdx.x; i < nb; i += 64) s += blockSums[i];
    for (int off = 32; off >= 1; off >>= 1) s += __shfl_down(s, off, 64);
    if (threadIdx.x == 0) out[0] = s;
}

extern "C" void kernel_launch(void* const* d_in, const int* in_sizes, int n_in,
                              void* d_out, int out_size, void* d_ws,
                              size_t ws_size, hipStream_t stream) {
    const float* scan = (const float*)d_in[0];   // [N,3]
    const float* tmpl = (const float*)d_in[1];   // [M,3]
    int N = in_sizes[0] / 3;
    int M = in_sizes[1] / 3;
    float* out = (float*)d_out;

    int MB = (M + 255) / 256;           // reduce-kernel blocks
    int GX = (M + MPB - 1) / MPB;       // main-kernel blocks along m

    // NC scan chunks: prefer 112 (=> GX*NC ~= 1120 blocks, ~4.4/CU).
    int NC = 112;
    while (NC > 1) {
        size_t need = (size_t)NC * M * 4 + (size_t)MB * 4;
        if (need <= ws_size) break;
        NC >>= 1;
    }

    char* ws = (char*)d_ws;
    float* part = (float*)ws;
    float* blockSums = (float*)(ws + (size_t)NC * M * 4);

    int chunk = (N + NC - 1) / NC;
    size_t shmem = (size_t)chunk * sizeof(float4);

    dim3 grid(GX, NC);
    chamfer_main<<<grid, BLK, shmem, stream>>>(scan, tmpl, part, M, N, chunk);
    chamfer_reduce<<<MB, 256, 0, stream>>>(tmpl, part, blockSums, M, NC);
    final_sum<<<1, 64, 0, stream>>>(blockSums, out, MB);
}

// Round 4
// 48.318 us; speedup vs baseline: 1.6402x; 1.1626x over previous
//
#include <hip/hip_runtime.h>
#include <math.h>

// Directional Chamfer: sum_m min_n ||t_m - s_n||^2.
// d2 = |t|^2 - q, q = 2 t.s - |s|^2 (maximize q over scan points).
// Main kernel: block (bx, c) covers 2048 template points x one 80-point scan
// chunk. Scan chunk packed into LDS as {2x,2y,2z,-|s|^2}; each thread owns
// TPT=8 template points -> 1 broadcast ds_read_b128 per 32 VALU ops.

#define TPT 8
#define BLK 256
#define MPB (TPT * BLK)   // 2048 template points per block
#define CHUNK 80          // scan points per chunk (250*80 = 20000 exactly)

__global__ void __launch_bounds__(BLK) chamfer_main(
    const float* __restrict__ scan, const float* __restrict__ tmpl,
    float* __restrict__ part, int M, int N) {
    __shared__ float4 lds[CHUNK];

    int c = blockIdx.y;
    int j0 = c * CHUNK;
    int cnt = N - j0;
    if (cnt > CHUNK) cnt = CHUNK;

    for (int i = threadIdx.x; i < cnt; i += BLK) {
        float x = scan[3 * (j0 + i) + 0];
        float y = scan[3 * (j0 + i) + 1];
        float z = scan[3 * (j0 + i) + 2];
        lds[i] = make_float4(2.f * x, 2.f * y, 2.f * z,
                             -(x * x + y * y + z * z));
    }
    __syncthreads();

    int base = blockIdx.x * MPB + threadIdx.x;
    float tx[TPT], ty[TPT], tz[TPT], q[TPT];
#pragma unroll
    for (int k = 0; k < TPT; ++k) {
        int m = base + k * BLK;
        if (m < M) {
            tx[k] = tmpl[3 * m + 0];
            ty[k] = tmpl[3 * m + 1];
            tz[k] = tmpl[3 * m + 2];
        } else {
            tx[k] = ty[k] = tz[k] = 0.f;
        }
        q[k] = -INFINITY;
    }

    if (cnt == CHUNK) {
#pragma unroll 8
        for (int j = 0; j < CHUNK; ++j) {
            float4 p = lds[j];  // all-lanes-same-address broadcast
#pragma unroll
            for (int k = 0; k < TPT; ++k)
                q[k] = fmaxf(q[k], fmaf(tx[k], p.x,
                                        fmaf(ty[k], p.y,
                                             fmaf(tz[k], p.z, p.w))));
        }
    } else {
        for (int j = 0; j < cnt; ++j) {
            float4 p = lds[j];
#pragma unroll
            for (int k = 0; k < TPT; ++k)
                q[k] = fmaxf(q[k], fmaf(tx[k], p.x,
                                        fmaf(ty[k], p.y,
                                             fmaf(tz[k], p.z, p.w))));
        }
    }

#pragma unroll
    for (int k = 0; k < TPT; ++k) {
        int m = base + k * BLK;
        if (m < M) part[(size_t)c * M + m] = q[k];
    }
}

// Per-template max over chunks + deterministic per-block partial sums.
__global__ void __launch_bounds__(256) chamfer_reduce(
    const float* __restrict__ tmpl, const float* __restrict__ part,
    float* __restrict__ blockSums, int M, int NC) {
    int m = blockIdx.x * blockDim.x + threadIdx.x;
    float d2 = 0.f;
    if (m < M) {
        float qmax = -INFINITY;
#pragma unroll 4
        for (int c = 0; c < NC; ++c)
            qmax = fmaxf(qmax, part[(size_t)c * M + m]);
        float x = tmpl[3 * m + 0];
        float y = tmpl[3 * m + 1];
        float z = tmpl[3 * m + 2];
        d2 = x * x + y * y + z * z - qmax;
        if (d2 < 0.f) d2 = 0.f;
    }
    for (int off = 32; off >= 1; off >>= 1) d2 += __shfl_down(d2, off, 64);
    __shared__ float wsum[4];
    int lane = threadIdx.x & 63;
    int wid = threadIdx.x >> 6;
    if (lane == 0) wsum[wid] = d2;
    __syncthreads();
    if (threadIdx.x == 0)
        blockSums[blockIdx.x] = wsum[0] + wsum[1] + wsum[2] + wsum[3];
}

__global__ void final_sum(const float* __restrict__ blockSums,
                          float* __restrict__ out, int nb) {
    float s = 0.f;
    for (int i = threadIdx.x; i < nb; i += 64) s += blockSums[i];
    for (int off = 32; off >= 1; off >>= 1) s += __shfl_down(s, off, 64);
    if (threadIdx.x == 0) out[0] = s;
}

extern "C" void kernel_launch(void* const* d_in, const int* in_sizes, int n_in,
                              void* d_out, int out_size, void* d_ws,
                              size_t ws_size, hipStream_t stream) {
    const float* scan = (const float*)d_in[0];   // [N,3]
    const float* tmpl = (const float*)d_in[1];   // [M,3]
    int N = in_sizes[0] / 3;
    int M = in_sizes[1] / 3;
    float* out = (float*)d_out;

    int GX = (M + MPB - 1) / MPB;      // 5 for M=10000
    int NC = (N + CHUNK - 1) / CHUNK;  // 250 for N=20000
    int MB = (M + 255) / 256;          // 40 reduce blocks

    char* ws = (char*)d_ws;
    float* part = (float*)ws;                               // NC*M floats
    float* blockSums = (float*)(ws + (size_t)NC * M * 4);   // MB floats

    dim3 grid(GX, NC);
    chamfer_main<<<grid, BLK, 0, stream>>>(scan, tmpl, part, M, N);
    chamfer_reduce<<<MB, 256, 0, stream>>>(tmpl, part, blockSums, M, NC);
    final_sum<<<1, 64, 0, stream>>>(blockSums, out, MB);
}

// Round 5
// 37.137 us; speedup vs baseline: 2.1340x; 1.3011x over previous
//
#include <hip/hip_runtime.h>
#include <math.h>

// Directional Chamfer: sum_m min_n ||t_m - s_n||^2.
// q = 2 t.s - |s|^2 (maximize), d2 = |t|^2 - qmax.
// Main: packed-fp32 math — v_pk_fma_f32 processes 2 scan points/instr,
// v_max3_f32 folds both maxes. 4 instr per (template x 2 scan pts).
// LDS pair-packed: pair p -> {2x0,2x1,2y0,2y1} and {2z0,2z1,-n0,-n1}.

typedef float v2 __attribute__((ext_vector_type(2)));

#define TPT 8
#define BLK 256
#define MPB (TPT * BLK)   // 2048 templates per block
#define CHUNK 100         // scan points per chunk (200*100 = 20000 exactly)
#define RED1 20           // chunks folded per reduce1 group

__device__ __forceinline__ v2 pk_fma(v2 a, v2 b, v2 c) {
    v2 d;
    asm("v_pk_fma_f32 %0, %1, %2, %3" : "=v"(d) : "v"(a), "v"(b), "v"(c));
    return d;
}
__device__ __forceinline__ float max3(float a, float b, float c) {
    float d;
    asm("v_max3_f32 %0, %1, %2, %3" : "=v"(d) : "v"(a), "v"(b), "v"(c));
    return d;
}

__global__ void __launch_bounds__(BLK) chamfer_main(
    const float* __restrict__ scan, const float* __restrict__ tmpl,
    float* __restrict__ part, unsigned* __restrict__ counter, int M, int N) {
    __shared__ float4 lds4[(CHUNK + 1) / 2 * 2];
    float* ldsf = (float*)lds4;

    if (blockIdx.x == 0 && blockIdx.y == 0 && threadIdx.x == 0) *counter = 0u;

    int c = blockIdx.y;
    int j0 = c * CHUNK;
    int cnt = N - j0;
    if (cnt > CHUNK) cnt = CHUNK;

    for (int i = threadIdx.x; i < cnt; i += BLK) {
        float x = scan[3 * (j0 + i) + 0];
        float y = scan[3 * (j0 + i) + 1];
        float z = scan[3 * (j0 + i) + 2];
        float* bp = &ldsf[(i >> 1) * 8];
        int h = i & 1;
        bp[0 + h] = 2.f * x;
        bp[2 + h] = 2.f * y;
        bp[4 + h] = 2.f * z;
        bp[6 + h] = -(x * x + y * y + z * z);
    }
    if ((cnt & 1) && threadIdx.x == 0) {  // pad odd tail so hi half is inert
        float* bp = &ldsf[(cnt >> 1) * 8];
        bp[1] = 0.f; bp[3] = 0.f; bp[5] = 0.f; bp[7] = -INFINITY;
    }
    __syncthreads();

    int base = blockIdx.x * MPB + threadIdx.x;
    v2 txx[TPT], tyy[TPT], tzz[TPT];
    float q[TPT];
#pragma unroll
    for (int k = 0; k < TPT; ++k) {
        int m = base + k * BLK;
        float x = 0.f, y = 0.f, z = 0.f;
        if (m < M) {
            x = tmpl[3 * m + 0];
            y = tmpl[3 * m + 1];
            z = tmpl[3 * m + 2];
        }
        txx[k] = (v2){x, x};
        tyy[k] = (v2){y, y};
        tzz[k] = (v2){z, z};
        q[k] = -INFINITY;
    }

    int npair = (cnt + 1) >> 1;
#pragma unroll 2
    for (int p = 0; p < npair; ++p) {
        float4 a = lds4[2 * p + 0];  // broadcast read: {2x0,2x1,2y0,2y1}
        float4 b = lds4[2 * p + 1];  // {2z0,2z1,-n0,-n1}
        v2 xx = (v2){a.x, a.y};
        v2 yy = (v2){a.z, a.w};
        v2 zz = (v2){b.x, b.y};
        v2 ww = (v2){b.z, b.w};
#pragma unroll
        for (int k = 0; k < TPT; ++k) {
            v2 r = pk_fma(tzz[k], zz, ww);
            r = pk_fma(tyy[k], yy, r);
            r = pk_fma(txx[k], xx, r);
            q[k] = max3(q[k], r.x, r.y);
        }
    }

#pragma unroll
    for (int k = 0; k < TPT; ++k) {
        int m = base + k * BLK;
        if (m < M) part[(size_t)c * M + m] = q[k];
    }
}

// Level-1 chunk-max: grid (ceil(M/256), G). Depth RED1, fully unrolled.
__global__ void __launch_bounds__(256) chamfer_reduce1(
    const float* __restrict__ part, float* __restrict__ qpart, int M, int NC) {
    int m = blockIdx.x * 256 + threadIdx.x;
    int g = blockIdx.y;
    if (m >= M) return;
    float qmax = -INFINITY;
#pragma unroll
    for (int c = 0; c < RED1; ++c) {
        int cc = g * RED1 + c;
        if (cc < NC) qmax = fmaxf(qmax, part[(size_t)cc * M + m]);
    }
    qpart[(size_t)g * M + m] = qmax;
}

// Level-2 max + d2 + block sums + fused last-block final sum.
__global__ void __launch_bounds__(256) chamfer_reduce2(
    const float* __restrict__ tmpl, const float* __restrict__ qpart,
    float* __restrict__ blockSums, unsigned* __restrict__ counter,
    float* __restrict__ out, int M, int G, int nb) {
    int bx = blockIdx.x;
    int m = bx * 256 + threadIdx.x;
    float d2 = 0.f;
    if (m < M) {
        float qmax = -INFINITY;
        for (int g = 0; g < G; ++g)
            qmax = fmaxf(qmax, qpart[(size_t)g * M + m]);
        float x = tmpl[3 * m + 0];
        float y = tmpl[3 * m + 1];
        float z = tmpl[3 * m + 2];
        d2 = fmaf(x, x, fmaf(y, y, z * z)) - qmax;
        if (d2 < 0.f) d2 = 0.f;
    }
    for (int off = 32; off >= 1; off >>= 1) d2 += __shfl_down(d2, off, 64);
    __shared__ float wsum[4];
    __shared__ int islast;
    int lane = threadIdx.x & 63;
    int wid = threadIdx.x >> 6;
    if (lane == 0) wsum[wid] = d2;
    __syncthreads();
    if (threadIdx.x == 0) {
        float bs = wsum[0] + wsum[1] + wsum[2] + wsum[3];
        __hip_atomic_store(&blockSums[bx], bs, __ATOMIC_RELEASE,
                           __HIP_MEMORY_SCOPE_AGENT);
        unsigned t = __hip_atomic_fetch_add(counter, 1u, __ATOMIC_ACQ_REL,
                                            __HIP_MEMORY_SCOPE_AGENT);
        islast = (t == (unsigned)(nb - 1));
    }
    __syncthreads();
    if (islast) {
        float s = 0.f;
        for (int i = threadIdx.x; i < nb; i += 64)
            s += __hip_atomic_load(&blockSums[i], __ATOMIC_RELAXED,
                                   __HIP_MEMORY_SCOPE_AGENT);
        if (threadIdx.x < 64) {
            for (int off = 32; off >= 1; off >>= 1)
                s += __shfl_down(s, off, 64);
            if (threadIdx.x == 0) out[0] = s;
        }
    }
}

extern "C" void kernel_launch(void* const* d_in, const int* in_sizes, int n_in,
                              void* d_out, int out_size, void* d_ws,
                              size_t ws_size, hipStream_t stream) {
    const float* scan = (const float*)d_in[0];   // [N,3]
    const float* tmpl = (const float*)d_in[1];   // [M,3]
    int N = in_sizes[0] / 3;
    int M = in_sizes[1] / 3;
    float* out = (float*)d_out;

    int GX = (M + MPB - 1) / MPB;        // 5
    int NC = (N + CHUNK - 1) / CHUNK;    // 200
    int G = (NC + RED1 - 1) / RED1;      // 10
    int MB = (M + 255) / 256;            // 40

    char* ws = (char*)d_ws;
    unsigned* counter = (unsigned*)ws;                    // 4 B
    float* blockSums = (float*)(ws + 256);                // MB floats
    float* qpart = (float*)(ws + 4096);                   // G*M floats
    size_t partOff = 4096 + ((size_t)G * M * 4 + 255) / 256 * 256;
    float* part = (float*)(ws + partOff);                 // NC*M floats

    dim3 grid(GX, NC);
    chamfer_main<<<grid, BLK, 0, stream>>>(scan, tmpl, part, counter, M, N);
    dim3 rgrid(MB, G);
    chamfer_reduce1<<<rgrid, 256, 0, stream>>>(part, qpart, M, NC);
    chamfer_reduce2<<<MB, 256, 0, stream>>>(tmpl, qpart, blockSums, counter,
                                            out, M, G, MB);
}